// Round 1
// 65.064 us; speedup vs baseline: 1.0027x; 1.0027x over previous
//
#include <hip/hip_runtime.h>
#include <math.h>

typedef __attribute__((ext_vector_type(8))) short short8;
typedef __attribute__((ext_vector_type(4))) float floatx4;

#define NIN 128
#define NOUT 128
#define NTH 128   // 2 waves/block, 1024 blocks

union FragU { unsigned u[4]; short8 s; };

// Split 8 fp32 (two float4) into bf16 hi (trunc) + bf16 lo (trunc residual).
__device__ __forceinline__ void cvt_frag(float4 a, float4 b, short8& hi, short8& lo) {
    const unsigned SEL = 0x07060302u;
    unsigned ua0 = __float_as_uint(a.x), ua1 = __float_as_uint(a.y);
    unsigned ua2 = __float_as_uint(a.z), ua3 = __float_as_uint(a.w);
    unsigned ub0 = __float_as_uint(b.x), ub1 = __float_as_uint(b.y);
    unsigned ub2 = __float_as_uint(b.z), ub3 = __float_as_uint(b.w);
    FragU h, l;
    h.u[0] = __builtin_amdgcn_perm(ua1, ua0, SEL);
    h.u[1] = __builtin_amdgcn_perm(ua3, ua2, SEL);
    h.u[2] = __builtin_amdgcn_perm(ub1, ub0, SEL);
    h.u[3] = __builtin_amdgcn_perm(ub3, ub2, SEL);
    float r0 = a.x - __uint_as_float(ua0 & 0xffff0000u);
    float r1 = a.y - __uint_as_float(ua1 & 0xffff0000u);
    float r2 = a.z - __uint_as_float(ua2 & 0xffff0000u);
    float r3 = a.w - __uint_as_float(ua3 & 0xffff0000u);
    float r4 = b.x - __uint_as_float(ub0 & 0xffff0000u);
    float r5 = b.y - __uint_as_float(ub1 & 0xffff0000u);
    float r6 = b.z - __uint_as_float(ub2 & 0xffff0000u);
    float r7 = b.w - __uint_as_float(ub3 & 0xffff0000u);
    l.u[0] = __builtin_amdgcn_perm(__float_as_uint(r1), __float_as_uint(r0), SEL);
    l.u[1] = __builtin_amdgcn_perm(__float_as_uint(r3), __float_as_uint(r2), SEL);
    l.u[2] = __builtin_amdgcn_perm(__float_as_uint(r5), __float_as_uint(r4), SEL);
    l.u[3] = __builtin_amdgcn_perm(__float_as_uint(r7), __float_as_uint(r6), SEL);
    hi = h.s; lo = l.s;
}

__device__ __forceinline__ float dot8(float4 a, float4 b, float4 c, float4 d, float s) {
    s = fmaf(a.x, c.x, s); s = fmaf(a.y, c.y, s);
    s = fmaf(a.z, c.z, s); s = fmaf(a.w, c.w, s);
    s = fmaf(b.x, d.x, s); s = fmaf(b.y, d.y, s);
    s = fmaf(b.z, d.z, s); s = fmaf(b.w, d.w, s);
    return s;
}

__global__ __launch_bounds__(NTH) void hyper_fused(
    const float* __restrict__ x,
    const float* __restrict__ w,
    const float* __restrict__ bia,
    float* __restrict__ out)
{
    const int wave = threadIdx.x >> 6;
    const int lane = threadIdx.x & 63;
    const int q = lane >> 4, i = lane & 15;

    // XCD-bijective swizzle: HW assigns XCD ~ blockIdx % 8 (8 XCDs).
    // Map so each XCD owns a CONTIGUOUS run of grid/8 blocks in tile space:
    // the 4 blocks sharing an m-tile of x, and all 8 n-tiles, become co-XCD
    // -> x fetched once into one L2, w/b fetched once per XCD (cold caches
    // every iteration: the harness's 268MB poison fill sweeps L2+L3).
    const int bid = blockIdx.x;
    const int cpx = gridDim.x >> 3;                 // blocks per XCD (grid % 8 == 0)
    const int tile = (bid & 7) * cpx + (bid >> 3);  // bijective for grid % 8 == 0

    const int waveid = tile * 2 + wave;
    const int m0 = (waveid >> 3) * 16;              // batch-row tile
    const int n0 = (waveid & 7) * 16;               // out-col tile

    const float* xr = x + (size_t)(m0 + i) * NIN + q * 8;   // A: m=i, k=q*8+j
    const float* wr = w + (size_t)(n0 + i) * NIN + q * 8;   // B: n=i, k=q*8+j
    const float* br = bia + (size_t)(n0 + i) * NIN + q * 8;

    // issue ALL global loads up front -> deep vmcnt pipeline, one latency wait
    float4 xa[4], xb[4], wa[4], wb[4], ba[4], bb[4];
    #pragma unroll
    for (int kc = 0; kc < 4; ++kc) {
        xa[kc] = *(const float4*)(xr + kc * 32);
        xb[kc] = *(const float4*)(xr + kc * 32 + 4);
        wa[kc] = *(const float4*)(wr + kc * 32);
        wb[kc] = *(const float4*)(wr + kc * 32 + 4);
        ba[kc] = *(const float4*)(br + kc * 32);
        bb[kc] = *(const float4*)(br + kc * 32 + 4);
    }

    floatx4 accW1 = {0.f, 0.f, 0.f, 0.f}, accW2 = {0.f, 0.f, 0.f, 0.f};
    floatx4 accB1 = {0.f, 0.f, 0.f, 0.f}, accB2 = {0.f, 0.f, 0.f, 0.f};
    float vv = 0.f, uu = 0.f, bw = 0.f, ww = 0.f;

    #pragma unroll
    for (int kc = 0; kc < 4; ++kc) {
        vv = dot8(xa[kc], xb[kc], xa[kc], xb[kc], vv);
        uu = dot8(ba[kc], bb[kc], ba[kc], bb[kc], uu);
        bw = dot8(ba[kc], bb[kc], wa[kc], wb[kc], bw);
        ww = dot8(wa[kc], wb[kc], wa[kc], wb[kc], ww);

        short8 ah, al, wh, wl, bh, bl;
        cvt_frag(xa[kc], xb[kc], ah, al);
        cvt_frag(wa[kc], wb[kc], wh, wl);
        cvt_frag(ba[kc], bb[kc], bh, bl);

        accW1 = __builtin_amdgcn_mfma_f32_16x16x32_bf16(ah, wh, accW1, 0, 0, 0);
        accB1 = __builtin_amdgcn_mfma_f32_16x16x32_bf16(ah, bh, accB1, 0, 0, 0);
        accW2 = __builtin_amdgcn_mfma_f32_16x16x32_bf16(ah, wl, accW2, 0, 0, 0);
        accB2 = __builtin_amdgcn_mfma_f32_16x16x32_bf16(ah, bl, accB2, 0, 0, 0);
        accW2 = __builtin_amdgcn_mfma_f32_16x16x32_bf16(al, wh, accW2, 0, 0, 0);
        accB2 = __builtin_amdgcn_mfma_f32_16x16x32_bf16(al, bh, accB2, 0, 0, 0);
    }

    // reduce stats across the 4 k-slices (lanes i, i+16, i+32, i+48)
    vv += __shfl_xor(vv, 16); vv += __shfl_xor(vv, 32);
    uu += __shfl_xor(uu, 16); uu += __shfl_xor(uu, 32);
    bw += __shfl_xor(bw, 16); bw += __shfl_xor(bw, 32);
    ww += __shfl_xor(ww, 16); ww += __shfl_xor(ww, 32);

    // vv[row] for this lane's 4 output rows (hoisted out of epilogue loop)
    float vvr[4];
    #pragma unroll
    for (int r = 0; r < 4; ++r) vvr[r] = __shfl(vv, q * 4 + r, 64);

    const float EPS = 1.1920928955078125e-7f;
    const float CLAMPV = 16.635532333438687f;
    const float INV_SMOOTH = 1.f / 50.f;
    const float SMOOTHF = 50.f;
    const float MAXNORM = 1.f - 1e-5f;

    const float beta = 1.f - uu;
    const float beta_c = fmaxf(beta, EPS);
    const float a_norm = fmaxf(beta_c * sqrtf(ww), 1e-15f);
    const float ba_ = beta_c * bw;
    const float outcoef = (2.f / beta_c) * a_norm;
    const float inv_anorm = 1.f / a_norm;

    #pragma unroll
    for (int r = 0; r < 4; ++r) {
        const int row = m0 + q * 4 + r;                   // C/D: row = quad*4 + reg
        const float vr = vvr[r];
        const float uv = -(accB1[r] + accB2[r]);
        const float xw = accW1[r] + accW2[r];
        const float dax = beta_c * xw;
        const float alpha = 1.f + 2.f * uv + vr;
        const float den = fmaxf(1.f + 2.f * uv + uu * vr, EPS);
        const float inv_den = 1.f / den;
        float suba = (beta * dax - alpha * ba_) * inv_den;
        float ss = (alpha * alpha * uu + 2.f * alpha * beta * uv + beta * beta * vr)
                   * (inv_den * inv_den);
        const float nrm = fmaxf(sqrtf(fmaxf(ss, 0.f)), 1e-15f);
        if (nrm > MAXNORM) {
            const float sc = MAXNORM / nrm;
            suba *= sc;
            ss *= sc * sc;
        }
        const float lam_sub = 2.f / fmaxf(1.f - ss, EPS);
        const float arg = lam_sub * suba * inv_anorm;
        const float t1 = SMOOTHF * (arg + CLAMPV);
        const float t2 = SMOOTHF * (arg - CLAMPV);
        const float sp1 = fmaxf(t1, 0.f) + __logf(1.f + __expf(-fabsf(t1)));
        const float sp2 = fmaxf(t2, 0.f) + __logf(1.f + __expf(-fabsf(t2)));
        const float scl = -CLAMPV + (sp1 - sp2) * INV_SMOOTH;
        const float s_ = fabsf(scl);
        const float sd = copysignf(__logf(s_ + sqrtf(fmaf(s_, s_, 1.f))), scl);
        out[(size_t)row * NOUT + n0 + i] = outcoef * sd;
    }
}

extern "C" void kernel_launch(void* const* d_in, const int* in_sizes, int n_in,
                              void* d_out, int out_size, void* d_ws, size_t ws_size,
                              hipStream_t stream) {
    const float* x = (const float*)d_in[0];
    const float* w = (const float*)d_in[1];
    const float* b = (const float*)d_in[2];
    float* out = (float*)d_out;
    const int B = in_sizes[0] / NIN;                       // 4096
    const int nblocks = (B / 16) * (NOUT / 16) / 2;        // 1024 (2 waves each)
    hipLaunchKernelGGL(hyper_fused, dim3(nblocks), dim3(NTH), 0, stream,
                       x, w, b, out);
}